// Round 4
// baseline (3472.490 us; speedup 1.0000x reference)
//
#include <hip/hip_runtime.h>
#include <hip/hip_bf16.h>

#define B_ 64
#define T_ 512
#define D_ 256
#define H_ 1024
#define RING 64          // h-history ring depth
#define PS 260           // partial row stride in floats

typedef __attribute__((ext_vector_type(8))) short short8;
typedef __attribute__((ext_vector_type(4))) float floatx4;

__device__ __forceinline__ unsigned short f2bf(float f){
  unsigned u = __builtin_bit_cast(unsigned, f);
  u = (u + 0x7fffu + ((u >> 16) & 1u)) >> 16;
  return (unsigned short)u;
}

__device__ __forceinline__ short8 pack8(floatx4 a, floatx4 b){
  short8 r;
  r[0]=(short)f2bf(a[0]); r[1]=(short)f2bf(a[1]); r[2]=(short)f2bf(a[2]); r[3]=(short)f2bf(a[3]);
  r[4]=(short)f2bf(b[0]); r[5]=(short)f2bf(b[1]); r[6]=(short)f2bf(b[2]); r[7]=(short)f2bf(b[3]);
  return r;
}

__device__ __forceinline__ float sigm(float v){ return 1.f/(1.f+__expf(-v)); }
__device__ __forceinline__ float tanh_f(float v){ return 1.f - 2.f/(1.f+__expf(2.f*v)); }

// Per-wave poll on ONE 64B counter line (this wave's 8 producers), with a monotone
// in-register cache: if the cached values already cover the target, no memory op at all.
__device__ __forceinline__ void gpoll(const unsigned long long* watch,
                                      unsigned& seen0, unsigned& seen1,
                                      unsigned tgt0, unsigned tgt1){
  if (__all(seen0 >= tgt0 && seen1 >= tgt1)) return;
  long g = 0;
  for (;;){
    unsigned long long v = __hip_atomic_load(watch, __ATOMIC_RELAXED, __HIP_MEMORY_SCOPE_AGENT);
    unsigned v0 = (unsigned)v, v1 = (unsigned)(v >> 32);
    seen0 = v0 > seen0 ? v0 : seen0;
    seen1 = v1 > seen1 ? v1 : seen1;
    if (__all(seen0 >= tgt0 && seen1 >= tgt1)) break;
    if (++g > (1L<<24)) break;   // safety valve; never hit in correct runs
  }
}

// h ring layout: MFMA-fragment tiles. slot*(64*1024) + jblk*1024 + row*16 + col  [shorts]
// seq layout: one qword per producer block j (per half): dword0 = layer0 seq, dword1 = layer1 seq.
//   Wave w of any block reads only jblks 8w..8w+7 -> its producers' counters are one 64B line.
//
// k-slice map (wave w):
//   L0: ks=0   -> x  chunk  k = w*32            (no recurrence dep; MFMA issued before poll)
//       ks=1-4 -> h0 chunk  k = 256 + w*128 + (ks-1)*32   (jblks 8w..8w+7)
//   L1: ks=0-3 -> h1 chunk  k = 1024 + w*128 + ks*32      (ready at step start; done under h0 wait)
//       ks=4-7 -> h0 chunk  k = w*128 + (ks-4)*32         (fresh; only 4 dependent k-steps)
template<int LAYER>
__device__ __forceinline__ void run_lstm(
    const float* __restrict__ x,
    const float* __restrict__ Wi, const float* __restrict__ Wh,
    const float* __restrict__ bi, const float* __restrict__ bh,
    unsigned* seq, unsigned short* h0h, unsigned short* h1h, float* h1f,
    int jbase, int j, int half,
    float* partial /*[64][PS]*/, float* c_st /*[32*16]*/, float* biasv /*[64]*/)
{
  constexpr int NK = LAYER ? 8 : 5;
  constexpr int KA = LAYER ? 1024 : 256;  // Wi K extent

  const int tid  = threadIdx.x;
  const int wave = tid >> 6;
  const int lane = tid & 63;
  const int n15  = lane & 15;
  const int kq   = (lane >> 4) * 8;

  // ---- one-time: weights -> registers (bf16) per the k-slice map.
  short8 bfr[4][NK];
  #pragma unroll
  for (int nt = 0; nt < 4; nt++){
    int n   = nt*16 + n15;
    int row = (n >> 4)*H_ + jbase + (n & 15);
    #pragma unroll
    for (int ks = 0; ks < NK; ks++){
      int k = (LAYER ? (ks < 4 ? 1024 + wave*128 + ks*32 : wave*128 + (ks-4)*32)
                     : (ks == 0 ? wave*32 : 256 + wave*128 + (ks-1)*32)) + kq;
      const float* s = (k < KA) ? (Wi + (size_t)row*KA + k)
                                : (Wh + (size_t)row*H_ + (k - KA));
      bfr[nt][ks] = pack8(*(const floatx4*)s, *(const floatx4*)(s + 4));
    }
  }
  if (tid < 64){
    int col = (tid >> 4)*H_ + jbase + (tid & 15);
    biasv[tid] = bi[col] + bh[col];
  }
  c_st[tid & 511] = 0.f;
  __syncthreads();

  // this wave's watch line: qword (half*64 + 8w + (lane&7))
  const unsigned long long* watch =
      (const unsigned long long*)seq + (size_t)(half*64 + wave*8 + (lane & 7));

  unsigned seen0 = 0, seen1 = 0;
  unsigned long long vf = 0;       // tail-prefetched counter line

  for (int t = 0; t < T_; t++){
    // merge tail prefetch into the monotone cache
    { unsigned p0 = (unsigned)vf, p1 = (unsigned)(vf >> 32);
      seen0 = p0 > seen0 ? p0 : seen0;
      seen1 = p1 > seen1 ? p1 : seen1; }

    // ---- L0: prefetch raw x for the x chunk (no recurrence dep)
    floatx4 xr[2][2];
    if constexpr (LAYER == 0){
      #pragma unroll
      for (int mt = 0; mt < 2; mt++){
        const float* xs = x + ((size_t)(half*32 + mt*16 + n15)*T_ + t)*D_ + wave*32 + kq;
        xr[mt][0] = *(const floatx4*)xs;
        xr[mt][1] = *(const floatx4*)(xs + 4);
      }
    }

    floatx4 acc[2][4];
    #pragma unroll
    for (int mt = 0; mt < 2; mt++)
      #pragma unroll
      for (int nt = 0; nt < 4; nt++)
        acc[mt][nt] = (floatx4)0.f;

    const unsigned short* h0t = h0h + ((size_t)((LAYER ? t : (t-1)) & (RING-1)) << 16);
    const unsigned short* h1t = h1h + ((size_t)((t-1) & (RING-1)) << 16);

    if constexpr (LAYER == 0){
      // early: x MFMAs issue now, drain under the poll
      {
        short8 afr0 = pack8(xr[0][0], xr[0][1]);
        short8 afr1 = pack8(xr[1][0], xr[1][1]);
        #pragma unroll
        for (int nt = 0; nt < 4; nt++){
          acc[0][nt] = __builtin_amdgcn_mfma_f32_16x16x32_bf16(afr0, bfr[nt][0], acc[0][nt], 0, 0, 0);
          acc[1][nt] = __builtin_amdgcn_mfma_f32_16x16x32_bf16(afr1, bfr[nt][0], acc[1][nt], 0, 0, 0);
        }
      }
      __builtin_amdgcn_sched_barrier(0);
      // wait: my 8 h0 producers >= t; ring guard on my 8 L1 consumers (collective over waves)
      gpoll(watch, seen0, seen1, (unsigned)t,
            (t >= RING) ? (unsigned)(t - RING + 1) : 0u);
      __builtin_amdgcn_sched_barrier(0);
      if (t > 0){
        #pragma unroll
        for (int ks = 1; ks < 5; ks++){
          const int hk = wave*128 + (ks-1)*32 + kq;
          const unsigned short* p = h0t + ((hk >> 4) << 10) + (hk & 15);
          short8 afr[2];
          #pragma unroll
          for (int mt = 0; mt < 2; mt++)
            afr[mt] = *(const short8*)(p + ((half*32 + mt*16 + n15) << 4));
          #pragma unroll
          for (int mt = 0; mt < 2; mt++)
            #pragma unroll
            for (int nt = 0; nt < 4; nt++)
              acc[mt][nt] = __builtin_amdgcn_mfma_f32_16x16x32_bf16(afr[mt], bfr[nt][ks], acc[mt][nt], 0, 0, 0);
        }
      }
    } else {
      // poll A: my 8 h1 peers >= t (usually satisfied by cache/prefetch; covers h1 ring collectively)
      gpoll(watch, seen0, seen1, 0u, (unsigned)t);
      __builtin_amdgcn_sched_barrier(0);
      if (t > 0){
        #pragma unroll
        for (int ks = 0; ks < 4; ks++){
          const int hk = wave*128 + ks*32 + kq;
          const unsigned short* p = h1t + ((hk >> 4) << 10) + (hk & 15);
          short8 afr[2];
          #pragma unroll
          for (int mt = 0; mt < 2; mt++)
            afr[mt] = *(const short8*)(p + ((half*32 + mt*16 + n15) << 4));
          #pragma unroll
          for (int mt = 0; mt < 2; mt++)
            #pragma unroll
            for (int nt = 0; nt < 4; nt++)
              acc[mt][nt] = __builtin_amdgcn_mfma_f32_16x16x32_bf16(afr[mt], bfr[nt][ks], acc[mt][nt], 0, 0, 0);
        }
      }
      __builtin_amdgcn_sched_barrier(0);
      // poll B: my 8 h0 producers fresh (>= t+1); only 4 dependent k-steps follow
      gpoll(watch, seen0, seen1, (unsigned)(t + 1), 0u);
      __builtin_amdgcn_sched_barrier(0);
      #pragma unroll
      for (int ks = 4; ks < 8; ks++){
        const int hk = wave*128 + (ks-4)*32 + kq;
        const unsigned short* p = h0t + ((hk >> 4) << 10) + (hk & 15);
        short8 afr[2];
        #pragma unroll
        for (int mt = 0; mt < 2; mt++)
          afr[mt] = *(const short8*)(p + ((half*32 + mt*16 + n15) << 4));
        #pragma unroll
        for (int mt = 0; mt < 2; mt++)
          #pragma unroll
          for (int nt = 0; nt < 4; nt++)
            acc[mt][nt] = __builtin_amdgcn_mfma_f32_16x16x32_bf16(afr[mt], bfr[nt][ks], acc[mt][nt], 0, 0, 0);
      }
    }

    // ---- spill K-slice partials: [n][wave*32+b] so 4 acc rows are one ds_write_b128
    #pragma unroll
    for (int mt = 0; mt < 2; mt++)
      #pragma unroll
      for (int nt = 0; nt < 4; nt++){
        int n  = nt*16 + n15;
        int b0 = mt*16 + (lane >> 4)*4;
        *(floatx4*)(partial + (size_t)n*PS + wave*32 + b0) = acc[mt][nt];
      }
    __syncthreads();

    // ---- gate reduction by ALL 512 threads: one (b, jj) each
    {
      int b = tid >> 4, jj = tid & 15;
      float g[4];
      #pragma unroll
      for (int q = 0; q < 4; q++){
        const float* p = partial + (size_t)(q*16 + jj)*PS + b;
        float s = biasv[q*16 + jj];
        #pragma unroll
        for (int ss = 0; ss < 8; ss++) s += p[ss*32];
        g[q] = s;
      }
      float co = c_st[tid];            // tid == b*16 + jj
      float si = sigm(g[0]), sf = sigm(g[1]), tg = tanh_f(g[2]), so = sigm(g[3]);
      float cn = sf*co + si*tg;
      float hn = so*tanh_f(cn);
      c_st[tid] = cn;
      unsigned hb = (unsigned)f2bf(hn);
      unsigned ob = (unsigned)__shfl_xor((int)hb, 1, 64);   // partner jj^1, same b
      if (!(jj & 1)){
        unsigned pk = hb | (ob << 16);
        unsigned short* dst = (LAYER ? h1h : h0h)
                            + ((size_t)(t & (RING-1)) << 16)
                            + ((size_t)j << 10) + ((size_t)(half*32 + b) << 4) + jj;
        __hip_atomic_store((unsigned*)dst, pk, __ATOMIC_RELAXED, __HIP_MEMORY_SCOPE_AGENT);
      }
      if (LAYER == 1 && t == T_-1)
        h1f[(size_t)(half*32 + b)*H_ + jbase + jj] = hn;
    }
    // tail prefetch of the watch line: completes under the barrier's vmcnt drain,
    // often lets the next step's first poll skip its RTT entirely.
    vf = __hip_atomic_load(watch, __ATOMIC_RELAXED, __HIP_MEMORY_SCOPE_AGENT);
    __syncthreads();   // all waves drain vmcnt (h stores visible) before the post
    if (tid == 0)
      __hip_atomic_store(seq + (size_t)(half*64 + j)*2 + LAYER, (unsigned)(t + 1),
                         __ATOMIC_RELAXED, __HIP_MEMORY_SCOPE_AGENT);
  }
}

__global__ __launch_bounds__(512, 2) void lstm_pk(
    const float* __restrict__ x,
    const float* __restrict__ Wih0, const float* __restrict__ Whh0,
    const float* __restrict__ bih0, const float* __restrict__ bhh0,
    const float* __restrict__ Wih1, const float* __restrict__ Whh1,
    const float* __restrict__ bih1, const float* __restrict__ bhh1,
    char* __restrict__ ws)
{
  __shared__ __align__(16) float partial[64*PS];   // 66.6 KB
  __shared__ float c_st[512];
  __shared__ float biasv[64];

  unsigned* seq       = (unsigned*)ws;                                    // 128 qwords (1 KB)
  unsigned short* h0h = (unsigned short*)(ws + (1<<20));                  // RING x 128KB tiles (8 MB)
  unsigned short* h1h = (unsigned short*)(ws + (1<<20) + RING*B_*H_*2);   // 8 MB
  float* h1f          = (float*)(ws + (1<<20) + 2*(size_t)RING*B_*H_*2);  // [64][1024] fp32

  const int bid = blockIdx.x;
  if (bid < 128){
    run_lstm<0>(x, Wih0, Whh0, bih0, bhh0, seq, h0h, h1h, h1f,
                (bid & 63)*16, bid & 63, bid >> 6, partial, c_st, biasv);
  } else {
    const int r = bid - 128;
    run_lstm<1>(x, Wih1, Whh1, bih1, bhh1, seq, h0h, h1h, h1f,
                (r & 63)*16, r & 63, r >> 6, partial, c_st, biasv);
  }
}

__global__ __launch_bounds__(128) void fc_k(
    const float* __restrict__ h1f, const float* __restrict__ Wfc,
    const float* __restrict__ bfc, float* __restrict__ out)
{
  __shared__ float hv[1024];
  int b = blockIdx.x, c = threadIdx.x;
  for (int i = c; i < 1024; i += 128) hv[i] = h1f[(size_t)b*1024 + i];
  __syncthreads();
  const floatx4* w4 = (const floatx4*)(Wfc + (size_t)c*1024);
  const floatx4* h4 = (const floatx4*)hv;
  float acc = 0.f;
  #pragma unroll 8
  for (int k = 0; k < 256; k++){
    floatx4 wv = w4[k];
    floatx4 hh = h4[k];
    acc += wv[0]*hh[0] + wv[1]*hh[1] + wv[2]*hh[2] + wv[3]*hh[3];
  }
  out[(size_t)b*128 + c] = acc + bfc[c];
}

extern "C" void kernel_launch(void* const* d_in, const int* in_sizes, int n_in,
                              void* d_out, int out_size, void* d_ws, size_t ws_size,
                              hipStream_t stream)
{
  const float* x    = (const float*)d_in[0];
  const float* Wih0 = (const float*)d_in[1];
  const float* Whh0 = (const float*)d_in[2];
  const float* bih0 = (const float*)d_in[3];
  const float* bhh0 = (const float*)d_in[4];
  const float* Wih1 = (const float*)d_in[5];
  const float* Whh1 = (const float*)d_in[6];
  const float* bih1 = (const float*)d_in[7];
  const float* bhh1 = (const float*)d_in[8];
  const float* Wfc  = (const float*)d_in[9];
  const float* bfc  = (const float*)d_in[10];

  // zero the seq counters (h ring slots written before first read; h[-1] by predication)
  hipMemsetAsync(d_ws, 0, 4096, stream);

  lstm_pk<<<256, 512, 0, stream>>>(x, Wih0, Whh0, bih0, bhh0, Wih1, Whh1, bih1, bhh1, (char*)d_ws);

  const float* h1f = (const float*)((char*)d_ws + (1<<20) + 2*(size_t)RING*B_*H_*2);
  fc_k<<<64, 128, 0, stream>>>(h1f, Wfc, bfc, (float*)d_out);
}